// Round 5
// baseline (782.024 us; speedup 1.0000x reference)
//
#include <hip/hip_runtime.h>
#include <hip/hip_bf16.h>

#define D_DIM 1024
#define U_DIM 1024
#define B_SZ  32
#define T_SZ  2048

typedef __bf16 bf16x8 __attribute__((ext_vector_type(8)));
typedef float f32x4 __attribute__((ext_vector_type(4)));
typedef unsigned short ushort8 __attribute__((ext_vector_type(8)));

#define AS1 __attribute__((address_space(1)))
#define AS3 __attribute__((address_space(3)))

__device__ __forceinline__ unsigned short f2bf(float f) {
    union { float f; unsigned u; } v;
    v.f = f;
    unsigned r = v.u + 0x7fffu + ((v.u >> 16) & 1u);  // RNE
    return (unsigned short)(r >> 16);
}

// XOR-swizzle for 128-byte rows (involution): spread 16B slot bits (4-6) by row bits (7-9).
__device__ __forceinline__ int swz128(int a) { return a ^ (((a >> 7) & 7) << 4); }

// ---------------- K0: values fp32 -> bf16, 64B/lane ----------------
__global__ __launch_bounds__(256) void vconv2(const float* __restrict__ v,
                                              unsigned short* __restrict__ o) {
    size_t i = ((size_t)blockIdx.x * 256 + threadIdx.x) * 16;
    f32x4 a0 = *reinterpret_cast<const f32x4*>(v + i);
    f32x4 a1 = *reinterpret_cast<const f32x4*>(v + i + 4);
    f32x4 a2 = *reinterpret_cast<const f32x4*>(v + i + 8);
    f32x4 a3 = *reinterpret_cast<const f32x4*>(v + i + 12);
    ushort8 h0, h1;
    h0[0] = f2bf(a0.x); h0[1] = f2bf(a0.y); h0[2] = f2bf(a0.z); h0[3] = f2bf(a0.w);
    h0[4] = f2bf(a1.x); h0[5] = f2bf(a1.y); h0[6] = f2bf(a1.z); h0[7] = f2bf(a1.w);
    h1[0] = f2bf(a2.x); h1[1] = f2bf(a2.y); h1[2] = f2bf(a2.z); h1[3] = f2bf(a2.w);
    h1[4] = f2bf(a3.x); h1[5] = f2bf(a3.y); h1[6] = f2bf(a3.z); h1[7] = f2bf(a3.w);
    *reinterpret_cast<ushort8*>(o + i) = h0;
    *reinterpret_cast<ushort8*>(o + i + 8) = h1;
}

// ---------------- K1: W2 [D,U] fp32 -> W2t [U,D] bf16 ----------------
__global__ __launch_bounds__(256) void w2_transpose(const float* __restrict__ W2,
                                                    unsigned short* __restrict__ W2t) {
    __shared__ float tile[32][33];
    int d0 = blockIdx.x * 32, u0 = blockIdx.y * 32;
    int tx = threadIdx.x, ty = threadIdx.y;  // 32 x 8
#pragma unroll
    for (int i = 0; i < 4; i++)
        tile[ty + 8 * i][tx] = W2[(size_t)(d0 + ty + 8 * i) * U_DIM + u0 + tx];
    __syncthreads();
#pragma unroll
    for (int i = 0; i < 4; i++)
        W2t[(size_t)(u0 + ty + 8 * i) * D_DIM + d0 + tx] = f2bf(tile[tx][ty + 8 * i]);
}

// ---------------- K2: qpb[b,u] = query@W1 + b1 + b2 (fp32), K split 4-way ----------------
__global__ __launch_bounds__(256) void qproj2(const float* __restrict__ query,
                                              const float* __restrict__ W1,
                                              const float* __restrict__ b1,
                                              const float* __restrict__ b2,
                                              float* __restrict__ qpb) {
    __shared__ float red[4][64];
    const int b = blockIdx.x;
    const int u0 = blockIdx.y * 64;
    const int tid = threadIdx.x;
    const int ul = tid & 63, kq = tid >> 6;
    const int u = u0 + ul;
    float acc = 0.f;
    const float* q = query + (size_t)b * D_DIM;
#pragma unroll 4
    for (int k = kq * 256; k < kq * 256 + 256; k++)
        acc += q[k] * W1[(size_t)k * U_DIM + u];
    red[kq][ul] = acc;
    __syncthreads();
    if (tid < 64) {
        float s = red[0][tid] + red[1][tid] + red[2][tid] + red[3][tid];
        qpb[(size_t)b * U_DIM + u0 + tid] = s + b1[u0 + tid] + b2[u0 + tid];
    }
}

// ---------------- K3: fused score GEMM — 8-phase schedule (T2+T3+T4+T5) ----------------
// Block: 256 rows x all 1024 u (4 passes of BN=256), BK=64, 8 waves (2m x 4n),
// wave tile 128x64, acc[8][4]. 64 K-tiles of 4 phases each.
// LDS: A 2dbuf x 2half x (2x64 rows)x64k = 64 KB; B same = 64 KB; +red 4K +qW/wV 8K.
// Half-tiles: A-half h = strip-local rows h*64..h*64+63 of each 128-row wave strip;
//             B-half h = strip-local u h*32..h*32+31 of each 64-u wave strip.
// Per phase: 12 ds_read_b128 + 2 global_load_lds (one half of tile s+1) +
//            barrier/lgkm0/16 MFMA(setprio)/counted-vmcnt/barrier.
__global__ __launch_bounds__(512, 2) void score_gemm8(const unsigned short* __restrict__ vbf,
                                                      const unsigned short* __restrict__ W2t,
                                                      const float* __restrict__ qpb,
                                                      const float* __restrict__ Wv,
                                                      float* __restrict__ scores) {
    __shared__ char smem[143360];
    float* redl = (float*)(smem + 131072);  // [4][256]
    float* qWl  = (float*)(smem + 135168);  // 1024 f32
    float* wVl  = (float*)(smem + 139264);  // 1024 f32

    const int tid = threadIdx.x, wave = tid >> 6, lane = tid & 63;
    const int lr = lane & 15, lk = lane >> 4;
    const int wm = wave >> 2, wn = wave & 3;  // wm 0..1 (row strip), wn 0..3 (u strip)
    const int row0 = blockIdx.x * 256;
    const int b = row0 >> 11;  // row0 / T_SZ

    // qpb/Wv -> LDS (so epilogue issues no vmem; vmcnt bookkeeping stays exact)
    qWl[tid]       = qpb[(size_t)b * U_DIM + tid];
    qWl[tid + 512] = qpb[(size_t)b * U_DIM + tid + 512];
    wVl[tid]       = Wv[tid];
    wVl[tid + 512] = Wv[tid + 512];

    // ---- precomputed addressing ----
    // ds_read offsets (within a half region; swizzled). m/n indices are half-local.
    int pa[4][2], pb[2][2];
#pragma unroll
    for (int mi = 0; mi < 4; mi++)
#pragma unroll
        for (int kk = 0; kk < 2; kk++)
            pa[mi][kk] = swz128((wm * 64 + mi * 16 + lr) * 128 + kk * 64 + lk * 16);
#pragma unroll
    for (int ni = 0; ni < 2; ni++)
#pragma unroll
        for (int kk = 0; kk < 2; kk++)
            pb[ni][kk] = swz128((wn * 32 + ni * 16 + lr) * 128 + kk * 64 + lk * 16);

    // stage-source element offsets (pre-swizzled per-lane global addresses; LDS dest linear)
    int aoff[2][2], boff[2][2];
#pragma unroll
    for (int j = 0; j < 2; j++) {
        const int ldst = (wave * 2 + j) * 1024 + lane * 16;
        const int sp = swz128(ldst);
        const int ri = sp >> 7, kb = (sp & 127) >> 1;
#pragma unroll
        for (int h = 0; h < 2; h++) {
            aoff[j][h] = (row0 + (ri >> 6) * 128 + h * 64 + (ri & 63)) * D_DIM + kb;
            boff[j][h] = ((ri >> 5) * 64 + h * 32 + (ri & 31)) * D_DIM + kb;
        }
    }

    auto stage_half = [&](int isA, int h, int t, int Dn) {
        const int ks = (t & 15) << 6;  // k element base
        if (isA) {
#pragma unroll
            for (int j = 0; j < 2; j++)
                __builtin_amdgcn_global_load_lds(
                    (const AS1 void*)(vbf + (size_t)aoff[j][h] + ks),
                    (AS3 void*)(smem + Dn * 32768 + h * 16384 + (wave * 2 + j) * 1024), 16, 0, 0);
        } else {
            const int ut = t >> 4;
#pragma unroll
            for (int j = 0; j < 2; j++)
                __builtin_amdgcn_global_load_lds(
                    (const AS1 void*)(W2t + (size_t)boff[j][h] + ut * 262144 + ks),
                    (AS3 void*)(smem + 65536 + Dn * 32768 + h * 16384 + (wave * 2 + j) * 1024), 16, 0, 0);
        }
    };

    f32x4 acc[8][4] = {};
    float s_acc[8][4] = {};

    // drain qW/wV register loads so vmcnt counts only stage loads
    asm volatile("s_waitcnt vmcnt(0)" ::: "memory");
    // prologue: tile 0's four halves, order [Ah0, Bh0, Bh1, Ah1]
    stage_half(1, 0, 0, 0);
    stage_half(0, 0, 0, 0);
    stage_half(0, 1, 0, 0);
    stage_half(1, 1, 0, 0);
    asm volatile("s_waitcnt vmcnt(4)" ::: "memory");  // Ah0(0), Bh0(0) landed
    __builtin_amdgcn_sched_barrier(0);
    __builtin_amdgcn_s_barrier();

// Phase: compute quadrant (MH, NH) of tile s from dbuf D; stage one half of tile s+1.
// WC: 0 = no wait, else vmcnt(WC-1) at phase end (before closing barrier).
#define PHASE(S, D, MH, NH, SOP, SH, WC)                                           \
    {                                                                              \
        bf16x8 af[4][2], bf[2][2];                                                 \
        _Pragma("unroll") for (int mi = 0; mi < 4; mi++)                           \
            _Pragma("unroll") for (int kk = 0; kk < 2; kk++)                       \
                af[mi][kk] = *(const bf16x8*)(smem + (D)*32768 + (MH)*16384 + pa[mi][kk]); \
        _Pragma("unroll") for (int ni = 0; ni < 2; ni++)                           \
            _Pragma("unroll") for (int kk = 0; kk < 2; kk++)                       \
                bf[ni][kk] = *(const bf16x8*)(smem + 65536 + (D)*32768 + (NH)*16384 + pb[ni][kk]); \
        if ((S) < 63) stage_half(SOP, SH, (S) + 1, 1 - (D));                       \
        __builtin_amdgcn_s_barrier();                                              \
        asm volatile("s_waitcnt lgkmcnt(0)" ::: "memory");                         \
        __builtin_amdgcn_sched_barrier(0);                                         \
        __builtin_amdgcn_s_setprio(1);                                             \
        _Pragma("unroll") for (int kk = 0; kk < 2; kk++)                           \
            _Pragma("unroll") for (int ni = 0; ni < 2; ni++)                       \
                _Pragma("unroll") for (int mi = 0; mi < 4; mi++)                   \
                    acc[(MH)*4 + mi][(NH)*2 + ni] = __builtin_amdgcn_mfma_f32_16x16x32_bf16( \
                        af[mi][kk], bf[ni][kk], acc[(MH)*4 + mi][(NH)*2 + ni], 0, 0, 0); \
        __builtin_amdgcn_s_setprio(0);                                             \
        if ((WC) == 5) asm volatile("s_waitcnt vmcnt(4)" ::: "memory");            \
        else if ((WC) == 3) asm volatile("s_waitcnt vmcnt(2)" ::: "memory");       \
        else if ((WC) == 1) asm volatile("s_waitcnt vmcnt(0)" ::: "memory");       \
        __builtin_amdgcn_sched_barrier(0);                                         \
        __builtin_amdgcn_s_barrier();                                              \
    }

// One K-tile: P1(m0,n0|stage Ah0,W4) P2(m0,n1|Bh0,W4) P3(m1,n0|Bh1,-) P4(m1,n1|Ah1,W4)
#define KTILE(S, D)                  \
    PHASE(S, D, 0, 0, 1, 0, 5)       \
    PHASE(S, D, 0, 1, 0, 0, 5)       \
    PHASE(S, D, 1, 0, 0, 1, 0)       \
    PHASE(S, D, 1, 1, 1, 1, 5)

#define EPI(UT)                                                                     \
    {                                                                               \
        _Pragma("unroll") for (int n = 0; n < 4; n++) {                             \
            const float qv = qWl[(UT)*256 + wn * 64 + n * 16 + lr];                 \
            const float wv = wVl[(UT)*256 + wn * 64 + n * 16 + lr];                 \
            _Pragma("unroll") for (int m = 0; m < 8; m++)                           \
                _Pragma("unroll") for (int r = 0; r < 4; r++) {                     \
                    float x = acc[m][n][r] + qv;                                    \
                    float e = __expf(2.0f * x);                                     \
                    s_acc[m][r] += (1.0f - 2.0f / (e + 1.0f)) * wv;                 \
                    acc[m][n][r] = 0.f;                                             \
                }                                                                   \
        }                                                                           \
    }

    for (int s2 = 0; s2 < 31; ++s2) {
        const int se = 2 * s2, so = 2 * s2 + 1;
        KTILE(se, 0)
        KTILE(so, 1)
        if (s2 == 7) EPI(0)
        else if (s2 == 15) EPI(1)
        else if (s2 == 23) EPI(2)
    }
    KTILE(62, 0)
    // s = 63: no staging; tail waits vmcnt(2) after P1, vmcnt(0) after P2
    PHASE(63, 1, 0, 0, 1, 0, 3)
    PHASE(63, 1, 0, 1, 0, 0, 1)
    PHASE(63, 1, 1, 0, 0, 1, 0)
    PHASE(63, 1, 1, 1, 1, 1, 0)
    EPI(3)
#undef PHASE
#undef KTILE
#undef EPI

    // reduce over the 16 lr-lanes
#pragma unroll
    for (int off = 1; off < 16; off <<= 1)
#pragma unroll
        for (int m = 0; m < 8; m++)
#pragma unroll
            for (int r = 0; r < 4; r++) s_acc[m][r] += __shfl_xor(s_acc[m][r], off);

    // cross-wave (4 wn) reduce via LDS, then direct store
    if (lr == 0) {
#pragma unroll
        for (int m = 0; m < 8; m++)
#pragma unroll
            for (int r = 0; r < 4; r++)
                redl[wn * 256 + wm * 128 + m * 16 + lk * 4 + r] = s_acc[m][r];
    }
    __syncthreads();
    if (tid < 256) {
        float s = redl[tid] + redl[256 + tid] + redl[512 + tid] + redl[768 + tid];
        scores[row0 + tid] = s;
    }
}

// ---------------- K4: softmax over T per batch (+ zero context output) ----------------
__global__ __launch_bounds__(256) void softmax_z(const float* __restrict__ scores,
                                                 float* __restrict__ wout,
                                                 float* __restrict__ out) {
    int b = blockIdx.x, tid = threadIdx.x;
    int lane = tid & 63, wave = tid >> 6;
    __shared__ float redm[4], reds[4];
    *reinterpret_cast<f32x4*>(out + (size_t)b * D_DIM + tid * 4) = (f32x4){0.f, 0.f, 0.f, 0.f};
    float v[8];
    float mx = -3.4e38f;
#pragma unroll
    for (int i = 0; i < 8; i++) {
        v[i] = scores[(size_t)b * T_SZ + tid + i * 256];
        mx = fmaxf(mx, v[i]);
    }
#pragma unroll
    for (int off = 1; off < 64; off <<= 1) mx = fmaxf(mx, __shfl_xor(mx, off));
    if (lane == 0) redm[wave] = mx;
    __syncthreads();
    mx = fmaxf(fmaxf(redm[0], redm[1]), fmaxf(redm[2], redm[3]));
    float sum = 0.f;
#pragma unroll
    for (int i = 0; i < 8; i++) {
        v[i] = __expf(v[i] - mx);
        sum += v[i];
    }
#pragma unroll
    for (int off = 1; off < 64; off <<= 1) sum += __shfl_xor(sum, off);
    if (lane == 0) reds[wave] = sum;
    __syncthreads();
    sum = reds[0] + reds[1] + reds[2] + reds[3];
    float inv = 1.0f / sum;
#pragma unroll
    for (int i = 0; i < 8; i++) wout[(size_t)b * T_SZ + tid + i * 256] = v[i] * inv;
}

// ---------------- K5: context[b,d] = sum_t w[b,t] * values[b,t,d] ----------------
__global__ __launch_bounds__(256) void context_k(const float* __restrict__ values,
                                                 const float* __restrict__ w,
                                                 float* __restrict__ out) {
    int b = blockIdx.x, tc = blockIdx.y;
    int d4 = threadIdx.x;
    f32x4 acc = {0.f, 0.f, 0.f, 0.f};
    const float* vb = values + (size_t)b * T_SZ * D_DIM;
    int t0 = tc * 64;
#pragma unroll 2
    for (int t = t0; t < t0 + 64; ++t) {
        float wt = w[(size_t)b * T_SZ + t];
        f32x4 v = *reinterpret_cast<const f32x4*>(vb + (size_t)t * D_DIM + d4 * 4);
        acc += wt * v;
    }
    float* o = out + (size_t)b * D_DIM + d4 * 4;
    atomicAdd(o + 0, acc.x);
    atomicAdd(o + 1, acc.y);
    atomicAdd(o + 2, acc.z);
    atomicAdd(o + 3, acc.w);
}

extern "C" void kernel_launch(void* const* d_in, const int* in_sizes, int n_in,
                              void* d_out, int out_size, void* d_ws, size_t ws_size,
                              hipStream_t stream) {
    (void)in_sizes; (void)n_in; (void)out_size; (void)ws_size;
    const float* query  = (const float*)d_in[0];
    const float* values = (const float*)d_in[1];
    const float* W1     = (const float*)d_in[2];
    const float* b1     = (const float*)d_in[3];
    const float* W2     = (const float*)d_in[4];
    const float* b2     = (const float*)d_in[5];
    const float* Wv     = (const float*)d_in[6];
    // d_in[7] = bv: softmax is shift-invariant; scores aren't an output -> unused.

    float* out  = (float*)d_out;             // [B,D] context
    float* wout = out + B_SZ * D_DIM;        // [B,T] attention weights

    const size_t VN = (size_t)B_SZ * T_SZ * D_DIM;  // 64M elems
    char* ws = (char*)d_ws;
    unsigned short* vbf = (unsigned short*)ws;                     // 128 MB
    float* scores = (float*)(ws + VN * 2);                         // 256 KB
    float* qpb = scores + 65536;                                   // 128 KB
    unsigned short* W2t = (unsigned short*)(qpb + 32768);          // 2 MB

    vconv2<<<16384, 256, 0, stream>>>(values, vbf);
    w2_transpose<<<dim3(32, 32), dim3(32, 8), 0, stream>>>(W2, W2t);
    qproj2<<<dim3(32, 16), 256, 0, stream>>>(query, W1, b1, b2, qpb);
    score_gemm8<<<256, 512, 0, stream>>>(vbf, W2t, qpb, Wv, scores);
    softmax_z<<<B_SZ, 256, 0, stream>>>(scores, wout, out);
    context_k<<<dim3(B_SZ, 32), 256, 0, stream>>>(values, wout, out);
}

// Round 6
// 352.248 us; speedup vs baseline: 2.2201x; 2.2201x over previous
//
#include <hip/hip_runtime.h>
#include <hip/hip_bf16.h>

#define D_DIM 1024
#define U_DIM 1024
#define B_SZ  32
#define T_SZ  2048

typedef __bf16 bf16x8 __attribute__((ext_vector_type(8)));
typedef float f32x4 __attribute__((ext_vector_type(4)));
typedef unsigned short ushort8 __attribute__((ext_vector_type(8)));

#define AS1 __attribute__((address_space(1)))
#define AS3 __attribute__((address_space(3)))

__device__ __forceinline__ unsigned short f2bf(float f) {
    union { float f; unsigned u; } v;
    v.f = f;
    unsigned r = v.u + 0x7fffu + ((v.u >> 16) & 1u);  // RNE
    return (unsigned short)(r >> 16);
}

// XOR-swizzle for 128-byte rows (involution): spread 16B slot bits (4-6) by row bits (7-9).
__device__ __forceinline__ int swz128(int a) { return a ^ (((a >> 7) & 7) << 4); }

// ---------------- K0: values fp32 -> bf16, 64B/lane ----------------
__global__ __launch_bounds__(256) void vconv2(const float* __restrict__ v,
                                              unsigned short* __restrict__ o) {
    size_t i = ((size_t)blockIdx.x * 256 + threadIdx.x) * 16;
    f32x4 a0 = *reinterpret_cast<const f32x4*>(v + i);
    f32x4 a1 = *reinterpret_cast<const f32x4*>(v + i + 4);
    f32x4 a2 = *reinterpret_cast<const f32x4*>(v + i + 8);
    f32x4 a3 = *reinterpret_cast<const f32x4*>(v + i + 12);
    ushort8 h0, h1;
    h0[0] = f2bf(a0.x); h0[1] = f2bf(a0.y); h0[2] = f2bf(a0.z); h0[3] = f2bf(a0.w);
    h0[4] = f2bf(a1.x); h0[5] = f2bf(a1.y); h0[6] = f2bf(a1.z); h0[7] = f2bf(a1.w);
    h1[0] = f2bf(a2.x); h1[1] = f2bf(a2.y); h1[2] = f2bf(a2.z); h1[3] = f2bf(a2.w);
    h1[4] = f2bf(a3.x); h1[5] = f2bf(a3.y); h1[6] = f2bf(a3.z); h1[7] = f2bf(a3.w);
    *reinterpret_cast<ushort8*>(o + i) = h0;
    *reinterpret_cast<ushort8*>(o + i + 8) = h1;
}

// ---------------- K1: W2 [D,U] fp32 -> W2t [U,D] bf16 ----------------
__global__ __launch_bounds__(256) void w2_transpose(const float* __restrict__ W2,
                                                    unsigned short* __restrict__ W2t) {
    __shared__ float tile[32][33];
    int d0 = blockIdx.x * 32, u0 = blockIdx.y * 32;
    int tx = threadIdx.x, ty = threadIdx.y;  // 32 x 8
#pragma unroll
    for (int i = 0; i < 4; i++)
        tile[ty + 8 * i][tx] = W2[(size_t)(d0 + ty + 8 * i) * U_DIM + u0 + tx];
    __syncthreads();
#pragma unroll
    for (int i = 0; i < 4; i++)
        W2t[(size_t)(u0 + ty + 8 * i) * D_DIM + d0 + tx] = f2bf(tile[tx][ty + 8 * i]);
}

// ---------------- K2: qpb[b,u] = query@W1 + b1 + b2 (fp32), K split 4-way ----------------
__global__ __launch_bounds__(256) void qproj2(const float* __restrict__ query,
                                              const float* __restrict__ W1,
                                              const float* __restrict__ b1,
                                              const float* __restrict__ b2,
                                              float* __restrict__ qpb) {
    __shared__ float red[4][64];
    const int b = blockIdx.x;
    const int u0 = blockIdx.y * 64;
    const int tid = threadIdx.x;
    const int ul = tid & 63, kq = tid >> 6;
    const int u = u0 + ul;
    float acc = 0.f;
    const float* q = query + (size_t)b * D_DIM;
#pragma unroll 4
    for (int k = kq * 256; k < kq * 256 + 256; k++)
        acc += q[k] * W1[(size_t)k * U_DIM + u];
    red[kq][ul] = acc;
    __syncthreads();
    if (tid < 64) {
        float s = red[0][tid] + red[1][tid] + red[2][tid] + red[3][tid];
        qpb[(size_t)b * U_DIM + u0 + tid] = s + b1[u0 + tid] + b2[u0 + tid];
    }
}

// ---------------- K3: fused score GEMM — 2-phase K-tiles, 3-slot ring, counted vmcnt ----------------
// Block: 256 rows; 8 u-passes of BN=128; BK=64 -> 128 K-tiles. 8 waves (wm 2 x wn 4),
// wave tile 128 rows x 32 u -> acc[8][2] f32x4 = 64 VGPR (register diet vs round 5).
// LDS ring: 3 slots x (A 32KB + B 16KB) = 144 KB + qW/wV 8 KB = 152 KB. 1 block/CU.
// Per K-tile: P1 (row-half 0): 12 ds_read_b128 + stage {B0,B1,A0}(t+2) + 16 MFMA.
//             P2 (row-half 1):  8 ds_read_b128 + stage {A1,A2,A3}(t+2) + 16 MFMA + vmcnt(6).
// vmcnt(6): 6 loads/wave/tile; t+2's 6 stay in flight, t+1's retire -> tile t+1 proven landed.
__global__ __launch_bounds__(512) void score_gemm8b(const unsigned short* __restrict__ vbf,
                                                    const unsigned short* __restrict__ W2t,
                                                    const float* __restrict__ qpb,
                                                    const float* __restrict__ Wv,
                                                    float* __restrict__ scores) {
    __shared__ char smem[155648];
    float* qWl = (float*)(smem + 147456);  // 1024 f32
    float* wVl = (float*)(smem + 151552);  // 1024 f32

    const int tid = threadIdx.x, wave = tid >> 6, lane = tid & 63;
    const int lr = lane & 15, lk = lane >> 4;
    const int wm = wave >> 2, wn = wave & 3;
    const int row0 = blockIdx.x * 256;
    const int b = row0 >> 11;  // row0 / T_SZ

    // qpb/Wv -> LDS (epilogue then issues no vmem; vmcnt bookkeeping stays exact)
    qWl[tid]       = qpb[(size_t)b * U_DIM + tid];
    qWl[tid + 512] = qpb[(size_t)b * U_DIM + tid + 512];
    wVl[tid]       = Wv[tid];
    wVl[tid + 512] = Wv[tid + 512];

    // ds_read offsets (swizzled; MH adds +8192 bytes, carry-free & swizzle-invariant)
    int pa[4][2], pb[2][2];
#pragma unroll
    for (int mi = 0; mi < 4; mi++)
#pragma unroll
        for (int kk = 0; kk < 2; kk++)
            pa[mi][kk] = swz128((wm * 128 + mi * 16 + lr) * 128 + kk * 64 + lk * 16);
#pragma unroll
    for (int ni = 0; ni < 2; ni++)
#pragma unroll
        for (int kk = 0; kk < 2; kk++)
            pb[ni][kk] = swz128((wn * 32 + ni * 16 + lr) * 128 + kk * 64 + lk * 16);

    // stage-source offsets: LDS dest linear, global source pre-swizzled (involution)
    int aoff[4], boff[2];
#pragma unroll
    for (int j = 0; j < 4; j++) {
        const int p = (wave * 4 + j) * 1024 + lane * 16;
        const int sp = swz128(p);
        aoff[j] = (row0 + (sp >> 7)) * D_DIM + ((sp & 127) >> 1);
    }
#pragma unroll
    for (int j = 0; j < 2; j++) {
        const int p = (wave * 2 + j) * 1024 + lane * 16;
        const int sp = swz128(p);
        boff[j] = (sp >> 7) * D_DIM + ((sp & 127) >> 1);
    }

    auto stageA = [&](int t, int sb, int j) {
        const int kb = (t & 15) << 6;
        __builtin_amdgcn_global_load_lds((const AS1 void*)(vbf + (size_t)(aoff[j] + kb)),
                                         (AS3 void*)(smem + sb + (wave * 4 + j) * 1024), 16, 0, 0);
    };
    auto stageB = [&](int t, int sb, int j) {
        const int off = boff[j] + ((t >> 4) << 17) + ((t & 15) << 6);
        __builtin_amdgcn_global_load_lds((const AS1 void*)(W2t + (size_t)off),
                                         (AS3 void*)(smem + sb + 32768 + (wave * 2 + j) * 1024), 16, 0, 0);
    };

    // prologue: drain qW/wV loads, then stage tiles 0,1
    asm volatile("s_waitcnt vmcnt(0)" ::: "memory");
    stageB(0, 0, 0); stageB(0, 0, 1);
    stageA(0, 0, 0); stageA(0, 0, 1); stageA(0, 0, 2); stageA(0, 0, 3);
    stageB(1, 49152, 0); stageB(1, 49152, 1);
    stageA(1, 49152, 0); stageA(1, 49152, 1); stageA(1, 49152, 2); stageA(1, 49152, 3);
    asm volatile("s_waitcnt vmcnt(6)" ::: "memory");  // tile 0 landed
    __syncthreads();

    f32x4 acc[8][2] = {};
    float s_acc[8][4] = {};

    int sb_c = 0;       // slot of tile t
    int sb_s = 98304;   // slot for tile t+2

    for (int t = 0; t < 128; ++t) {
        bf16x8 bq[2][2];
        {   // ---- P1: row-half MH=0 ----
            bf16x8 af[4][2];
#pragma unroll
            for (int mi = 0; mi < 4; mi++)
#pragma unroll
                for (int kk = 0; kk < 2; kk++)
                    af[mi][kk] = *(const bf16x8*)(smem + sb_c + pa[mi][kk]);
#pragma unroll
            for (int ni = 0; ni < 2; ni++)
#pragma unroll
                for (int kk = 0; kk < 2; kk++)
                    bq[ni][kk] = *(const bf16x8*)(smem + sb_c + 32768 + pb[ni][kk]);
            if (t < 126) { stageB(t + 2, sb_s, 0); stageB(t + 2, sb_s, 1); stageA(t + 2, sb_s, 0); }
            __builtin_amdgcn_s_barrier();
            asm volatile("s_waitcnt lgkmcnt(0)" ::: "memory");
            __builtin_amdgcn_sched_barrier(0);
            __builtin_amdgcn_s_setprio(1);
#pragma unroll
            for (int kk = 0; kk < 2; kk++)
#pragma unroll
                for (int ni = 0; ni < 2; ni++)
#pragma unroll
                    for (int mi = 0; mi < 4; mi++)
                        acc[mi][ni] = __builtin_amdgcn_mfma_f32_16x16x32_bf16(
                            af[mi][kk], bq[ni][kk], acc[mi][ni], 0, 0, 0);
            __builtin_amdgcn_s_setprio(0);
            __builtin_amdgcn_sched_barrier(0);
            __builtin_amdgcn_s_barrier();
        }
        {   // ---- P2: row-half MH=1 (B frags kept live from P1) ----
            bf16x8 af[4][2];
#pragma unroll
            for (int mi = 0; mi < 4; mi++)
#pragma unroll
                for (int kk = 0; kk < 2; kk++)
                    af[mi][kk] = *(const bf16x8*)(smem + sb_c + 8192 + pa[mi][kk]);
            if (t < 126) { stageA(t + 2, sb_s, 1); stageA(t + 2, sb_s, 2); stageA(t + 2, sb_s, 3); }
            __builtin_amdgcn_s_barrier();
            asm volatile("s_waitcnt lgkmcnt(0)" ::: "memory");
            __builtin_amdgcn_sched_barrier(0);
            __builtin_amdgcn_s_setprio(1);
#pragma unroll
            for (int kk = 0; kk < 2; kk++)
#pragma unroll
                for (int ni = 0; ni < 2; ni++)
#pragma unroll
                    for (int mi = 0; mi < 4; mi++)
                        acc[4 + mi][ni] = __builtin_amdgcn_mfma_f32_16x16x32_bf16(
                            af[mi][kk], bq[ni][kk], acc[4 + mi][ni], 0, 0, 0);
            __builtin_amdgcn_s_setprio(0);
            if (t < 126)       asm volatile("s_waitcnt vmcnt(6)" ::: "memory");
            else if (t == 126) asm volatile("s_waitcnt vmcnt(0)" ::: "memory");
            __builtin_amdgcn_sched_barrier(0);
            __builtin_amdgcn_s_barrier();
        }
        sb_c = (sb_c == 98304) ? 0 : sb_c + 49152;
        sb_s = (sb_s == 98304) ? 0 : sb_s + 49152;

        if ((t & 15) == 15) {  // end of a BN=128 u-pass: tanh epilogue
            const int ut = t >> 4;
#pragma unroll
            for (int ni = 0; ni < 2; ni++) {
                const int u = ut * 128 + wn * 32 + ni * 16 + lr;
                const float qv = qWl[u];
                const float wv = wVl[u];
#pragma unroll
                for (int m = 0; m < 8; m++)
#pragma unroll
                    for (int r = 0; r < 4; r++) {
                        float x = acc[m][ni][r] + qv;
                        float e = __expf(2.0f * x);
                        s_acc[m][r] += (1.0f - 2.0f / (e + 1.0f)) * wv;
                        acc[m][ni][r] = 0.f;
                    }
            }
        }
    }

    // reduce over the 16 lr-lanes
#pragma unroll
    for (int off = 1; off < 16; off <<= 1)
#pragma unroll
        for (int m = 0; m < 8; m++)
#pragma unroll
            for (int r = 0; r < 4; r++) s_acc[m][r] += __shfl_xor(s_acc[m][r], off);

    // cross-wave (4 wn) reduce via LDS (ring is dead), then direct store
    __syncthreads();
    float* redl = (float*)smem;  // [4][256]
    if (lr == 0) {
#pragma unroll
        for (int m = 0; m < 8; m++)
#pragma unroll
            for (int r = 0; r < 4; r++)
                redl[wn * 256 + wm * 128 + m * 16 + lk * 4 + r] = s_acc[m][r];
    }
    __syncthreads();
    if (tid < 256) {
        float s = redl[tid] + redl[256 + tid] + redl[512 + tid] + redl[768 + tid];
        scores[row0 + tid] = s;
    }
}

// ---------------- K4: softmax over T per batch (+ zero context output) ----------------
__global__ __launch_bounds__(256) void softmax_z(const float* __restrict__ scores,
                                                 float* __restrict__ wout,
                                                 float* __restrict__ out) {
    int b = blockIdx.x, tid = threadIdx.x;
    int lane = tid & 63, wave = tid >> 6;
    __shared__ float redm[4], reds[4];
    *reinterpret_cast<f32x4*>(out + (size_t)b * D_DIM + tid * 4) = (f32x4){0.f, 0.f, 0.f, 0.f};
    float v[8];
    float mx = -3.4e38f;
#pragma unroll
    for (int i = 0; i < 8; i++) {
        v[i] = scores[(size_t)b * T_SZ + tid + i * 256];
        mx = fmaxf(mx, v[i]);
    }
#pragma unroll
    for (int off = 1; off < 64; off <<= 1) mx = fmaxf(mx, __shfl_xor(mx, off));
    if (lane == 0) redm[wave] = mx;
    __syncthreads();
    mx = fmaxf(fmaxf(redm[0], redm[1]), fmaxf(redm[2], redm[3]));
    float sum = 0.f;
#pragma unroll
    for (int i = 0; i < 8; i++) {
        v[i] = __expf(v[i] - mx);
        sum += v[i];
    }
#pragma unroll
    for (int off = 1; off < 64; off <<= 1) sum += __shfl_xor(sum, off);
    if (lane == 0) reds[wave] = sum;
    __syncthreads();
    sum = reds[0] + reds[1] + reds[2] + reds[3];
    float inv = 1.0f / sum;
#pragma unroll
    for (int i = 0; i < 8; i++) wout[(size_t)b * T_SZ + tid + i * 256] = v[i] * inv;
}

// ---------------- K5: context[b,d] = sum_t w[b,t] * values[b,t,d] ----------------
__global__ __launch_bounds__(256) void context_k(const float* __restrict__ values,
                                                 const float* __restrict__ w,
                                                 float* __restrict__ out) {
    int b = blockIdx.x, tc = blockIdx.y;
    int d4 = threadIdx.x;
    f32x4 acc = {0.f, 0.f, 0.f, 0.f};
    const float* vb = values + (size_t)b * T_SZ * D_DIM;
    int t0 = tc * 64;
#pragma unroll 2
    for (int t = t0; t < t0 + 64; ++t) {
        float wt = w[(size_t)b * T_SZ + t];
        f32x4 v = *reinterpret_cast<const f32x4*>(vb + (size_t)t * D_DIM + d4 * 4);
        acc += wt * v;
    }
    float* o = out + (size_t)b * D_DIM + d4 * 4;
    atomicAdd(o + 0, acc.x);
    atomicAdd(o + 1, acc.y);
    atomicAdd(o + 2, acc.z);
    atomicAdd(o + 3, acc.w);
}

extern "C" void kernel_launch(void* const* d_in, const int* in_sizes, int n_in,
                              void* d_out, int out_size, void* d_ws, size_t ws_size,
                              hipStream_t stream) {
    (void)in_sizes; (void)n_in; (void)out_size; (void)ws_size;
    const float* query  = (const float*)d_in[0];
    const float* values = (const float*)d_in[1];
    const float* W1     = (const float*)d_in[2];
    const float* b1     = (const float*)d_in[3];
    const float* W2     = (const float*)d_in[4];
    const float* b2     = (const float*)d_in[5];
    const float* Wv     = (const float*)d_in[6];
    // d_in[7] = bv: softmax is shift-invariant; scores aren't an output -> unused.

    float* out  = (float*)d_out;             // [B,D] context
    float* wout = out + B_SZ * D_DIM;        // [B,T] attention weights

    const size_t VN = (size_t)B_SZ * T_SZ * D_DIM;  // 64M elems
    char* ws = (char*)d_ws;
    unsigned short* vbf = (unsigned short*)ws;                     // 128 MB
    float* scores = (float*)(ws + VN * 2);                         // 256 KB
    float* qpb = scores + 65536;                                   // 128 KB
    unsigned short* W2t = (unsigned short*)(qpb + 32768);          // 2 MB

    vconv2<<<16384, 256, 0, stream>>>(values, vbf);
    w2_transpose<<<dim3(32, 32), dim3(32, 8), 0, stream>>>(W2, W2t);
    qproj2<<<dim3(32, 16), 256, 0, stream>>>(query, W1, b1, b2, qpb);
    score_gemm8b<<<256, 512, 0, stream>>>(vbf, W2t, qpb, Wv, scores);
    softmax_z<<<B_SZ, 256, 0, stream>>>(scores, wout, out);
    context_k<<<dim3(B_SZ, 32), 256, 0, stream>>>(values, wout, out);
}

// Round 7
// 294.573 us; speedup vs baseline: 2.6548x; 1.1958x over previous
//
#include <hip/hip_runtime.h>
#include <hip/hip_bf16.h>

#define D_DIM 1024
#define U_DIM 1024
#define B_SZ  32
#define T_SZ  2048

typedef __bf16 bf16x8 __attribute__((ext_vector_type(8)));
typedef float f32x4 __attribute__((ext_vector_type(4)));
typedef unsigned short ushort8 __attribute__((ext_vector_type(8)));
typedef unsigned short ushort4_t __attribute__((ext_vector_type(4)));

#define AS1 __attribute__((address_space(1)))
#define AS3 __attribute__((address_space(3)))

__device__ __forceinline__ unsigned short f2bf(float f) {
    union { float f; unsigned u; } v;
    v.f = f;
    unsigned r = v.u + 0x7fffu + ((v.u >> 16) & 1u);  // RNE
    return (unsigned short)(r >> 16);
}
__device__ __forceinline__ float bf2f(unsigned short h) {
    union { unsigned u; float f; } v;
    v.u = (unsigned)h << 16;
    return v.f;
}

// ---------------- K0: values fp32 -> bf16, 64B/lane ----------------
__global__ __launch_bounds__(256) void vconv2(const float* __restrict__ v,
                                              unsigned short* __restrict__ o) {
    size_t i = ((size_t)blockIdx.x * 256 + threadIdx.x) * 16;
    f32x4 a0 = *reinterpret_cast<const f32x4*>(v + i);
    f32x4 a1 = *reinterpret_cast<const f32x4*>(v + i + 4);
    f32x4 a2 = *reinterpret_cast<const f32x4*>(v + i + 8);
    f32x4 a3 = *reinterpret_cast<const f32x4*>(v + i + 12);
    ushort8 h0, h1;
    h0[0] = f2bf(a0.x); h0[1] = f2bf(a0.y); h0[2] = f2bf(a0.z); h0[3] = f2bf(a0.w);
    h0[4] = f2bf(a1.x); h0[5] = f2bf(a1.y); h0[6] = f2bf(a1.z); h0[7] = f2bf(a1.w);
    h1[0] = f2bf(a2.x); h1[1] = f2bf(a2.y); h1[2] = f2bf(a2.z); h1[3] = f2bf(a2.w);
    h1[4] = f2bf(a3.x); h1[5] = f2bf(a3.y); h1[6] = f2bf(a3.z); h1[7] = f2bf(a3.w);
    *reinterpret_cast<ushort8*>(o + i) = h0;
    *reinterpret_cast<ushort8*>(o + i + 8) = h1;
}

// ---------------- K1: W2 [D,U] fp32 -> W2t [U,D] bf16 ----------------
__global__ __launch_bounds__(256) void w2_transpose(const float* __restrict__ W2,
                                                    unsigned short* __restrict__ W2t) {
    __shared__ float tile[32][33];
    int d0 = blockIdx.x * 32, u0 = blockIdx.y * 32;
    int tx = threadIdx.x, ty = threadIdx.y;  // 32 x 8
#pragma unroll
    for (int i = 0; i < 4; i++)
        tile[ty + 8 * i][tx] = W2[(size_t)(d0 + ty + 8 * i) * U_DIM + u0 + tx];
    __syncthreads();
#pragma unroll
    for (int i = 0; i < 4; i++)
        W2t[(size_t)(u0 + ty + 8 * i) * D_DIM + d0 + tx] = f2bf(tile[tx][ty + 8 * i]);
}

// ---------------- K2: qpb[b,u] = query@W1 + b1 + b2 (fp32), K split 4-way ----------------
__global__ __launch_bounds__(256) void qproj2(const float* __restrict__ query,
                                              const float* __restrict__ W1,
                                              const float* __restrict__ b1,
                                              const float* __restrict__ b2,
                                              float* __restrict__ qpb) {
    __shared__ float red[4][64];
    const int b = blockIdx.x;
    const int u0 = blockIdx.y * 64;
    const int tid = threadIdx.x;
    const int ul = tid & 63, kq = tid >> 6;
    const int u = u0 + ul;
    float acc = 0.f;
    const float* q = query + (size_t)b * D_DIM;
#pragma unroll 4
    for (int k = kq * 256; k < kq * 256 + 256; k++)
        acc += q[k] * W1[(size_t)k * U_DIM + u];
    red[kq][ul] = acc;
    __syncthreads();
    if (tid < 64) {
        float s = red[0][tid] + red[1][tid] + red[2][tid] + red[3][tid];
        qpb[(size_t)b * U_DIM + u0 + tid] = s + b1[u0 + tid] + b2[u0 + tid];
    }
}

// ---------------- K3: fused score GEMM — 4-phase K-tiles, 2-slot dbuf, counted vmcnt ----------------
// Block: 256 rows; 4 u-passes of BN=256; BK=64 -> 64 K-tiles. 8 waves (wm2 x wn4),
// wave tile 128x64, acc[8][4] = 128 (AGPR). LDS: 2 slots x (A 32K + B 32K) = 128 KB
// + qW/wV 8 KB + red 4 KB = 140 KB. 1 block/CU, 2 waves/SIMD, 256-reg cap via (512,2).
//
// Phases per tile t (slot c = t&1; stage tile t+1 -> slot n = c^1):
//   P1 (MH0,NH0): read af_mh0(8) + bq_nh0(4); stage A-half0(t+1); 16 MFMA; vmcnt(2)
//   P2 (MH0,NH1): read bq_nh1(4);             stage B-half0(t+1); 16 MFMA
//   P3 (MH1,NH0): read af_mh1(8) + bq_nh0(4); stage A-half1(t+1); 16 MFMA
//   P4 (MH1,NH1): read bq_nh1(4);             stage B-half1(t+1); 16 MFMA; vmcnt(4)
// (one s_barrier per phase, after the gate)
//
// Stage-halves == compute-quadrant footprints by construction:
//   A-half h = LDS rows {0-63,128-191} (h=0) / {64-127,192-255} (h=1)  == MH rows of both wm strips
//   B-half h = LDS u' {s*64 + h*32 .. +31, s=0..3}                     == NH u of all wn strips
// Per-wave vmcnt ledger (2 loads per half, oldest-first):
//   end P4(t-1): out=[A0,B0,A1,B1](t) =8 -> vmcnt(4) retires A0,B0 (needed P1(t))
//   end P1(t):   out=[A1,B1](t)+[A0](t+1)=6 -> vmcnt(2) retires A1,B1 (needed P3,P2)
//   P2..P4 issue B0,A1,B1(t+1): out=8 at P4 end -> loop. Tail t=63: vmcnt(0) at P1-end.
__global__ __launch_bounds__(512, 2) void score_gemm9(const unsigned short* __restrict__ vbf,
                                                      const unsigned short* __restrict__ W2t,
                                                      const float* __restrict__ qpb,
                                                      const float* __restrict__ Wv,
                                                      float* __restrict__ scores) {
    __shared__ char smem[143360];
    float* qWl = (float*)(smem + 131072);  // 1024 f32
    float* wVl = (float*)(smem + 135168);  // 1024 f32
    float* redl = (float*)(smem + 139264); // [4][256]

    const int tid = threadIdx.x, wave = tid >> 6, lane = tid & 63;
    const int lr = lane & 15, lk = lane >> 4;
    const int wm = wave >> 2, wn = wave & 3;
    const int row0 = blockIdx.x * 256;
    const int b = row0 >> 11;

    // qpb/Wv -> LDS (epilogues issue no vmem; vmcnt ledger stays exact)
    qWl[tid]       = qpb[(size_t)b * U_DIM + tid];
    qWl[tid + 512] = qpb[(size_t)b * U_DIM + tid + 512];
    wVl[tid]       = Wv[tid];
    wVl[tid + 512] = Wv[tid + 512];

    // ds_read swizzled bases (row&7 == lr&7 for all mi/mh/ni/nh deltas -> affine-safe)
    int pa[2], pb[2];
#pragma unroll
    for (int kk = 0; kk < 2; kk++) {
        pa[kk] = (wm * 128 + lr) * 128 + (((kk * 4 + lk) ^ (lr & 7)) << 4);
        pb[kk] = (wn * 64 + lr) * 128 + (((kk * 4 + lk) ^ (lr & 7)) << 4);
    }

    // stage addressing: LDS dest linear, global source pre-swizzled (involution).
    // linear dest L -> row=L>>7 (swizzle preserves), col' = (lane&7)^(lane>>3) slot.
    const int ecol = ((lane & 7) ^ (lane >> 3)) * 8;  // element offset within row
    int aoff[2], dstA[2], boff[2], dstB[2];
#pragma unroll
    for (int j = 0; j < 2; j++) {
        const int rowA = j * 128 + wave * 8 + (lane >> 3);
        aoff[j] = (row0 + rowA) * 1024 + ecol;
        dstA[j] = j * 16384 + wave * 1024 + lane * 16;
        const int idx = wave * 2 + j, s = idx >> 2, l = idx & 3;
        const int rowB = s * 64 + l * 8 + (lane >> 3);
        boff[j] = rowB * 1024 + ecol;
        dstB[j] = 32768 + s * 8192 + l * 1024 + lane * 16;
    }

    f32x4 acc[8][4] = {};
    float s_acc[8][4] = {};

#define SA(h, tkn, nb)                                                              \
    { _Pragma("unroll") for (int j = 0; j < 2; j++)                                 \
        __builtin_amdgcn_global_load_lds(                                           \
            (const AS1 void*)(vbf + (size_t)(aoff[j] + (h) * 65536 + (tkn) * 64)),  \
            (AS3 void*)(smem + (nb) + dstA[j] + (h) * 8192), 16, 0, 0); }
#define SB(h, tkn, psn, nb)                                                         \
    { _Pragma("unroll") for (int j = 0; j < 2; j++)                                 \
        __builtin_amdgcn_global_load_lds(                                           \
            (const AS1 void*)(W2t + (size_t)(boff[j] + (psn) * 262144 + (h) * 32768 + (tkn) * 64)), \
            (AS3 void*)(smem + (nb) + dstB[j] + (h) * 4096), 16, 0, 0); }
#define VM(N) asm volatile("s_waitcnt vmcnt(" #N ")" ::: "memory")

    // prologue: drain qW/wV traffic, stage tile 0 halves in ledger order A0,B0,A1,B1
    asm volatile("s_waitcnt vmcnt(0) lgkmcnt(0)" ::: "memory");
    SA(0, 0, 0) SB(0, 0, 0, 0) SA(1, 0, 0) SB(1, 0, 0, 0)
    VM(4);
    __builtin_amdgcn_s_barrier();

#define RAF(MH, cb)                                                                 \
    _Pragma("unroll") for (int mi = 0; mi < 4; mi++)                                \
        _Pragma("unroll") for (int kk = 0; kk < 2; kk++)                            \
            af[mi][kk] = *(const bf16x8*)(smem + (cb) + (MH) * 8192 + mi * 2048 + pa[kk]);

#define PH(MH, NH, cb, PRE, POST)                                                   \
    {                                                                               \
        bf16x8 bq[2][2];                                                            \
        _Pragma("unroll") for (int ni = 0; ni < 2; ni++)                            \
            _Pragma("unroll") for (int kk = 0; kk < 2; kk++)                        \
                bq[ni][kk] = *(const bf16x8*)(smem + (cb) + 32768 + (NH) * 4096 +   \
                                              ni * 2048 + pb[kk]);                  \
        PRE;                                                                        \
        __builtin_amdgcn_s_setprio(1);                                              \
        _Pragma("unroll") for (int kk = 0; kk < 2; kk++)                            \
            _Pragma("unroll") for (int ni = 0; ni < 2; ni++)                        \
                _Pragma("unroll") for (int mi = 0; mi < 4; mi++)                    \
                    acc[(MH) * 4 + mi][(NH) * 2 + ni] =                             \
                        __builtin_amdgcn_mfma_f32_16x16x32_bf16(                    \
                            af[mi][kk], bq[ni][kk], acc[(MH) * 4 + mi][(NH) * 2 + ni], 0, 0, 0); \
        __builtin_amdgcn_s_setprio(0);                                              \
        POST;                                                                       \
        __builtin_amdgcn_s_barrier();                                               \
    }

    for (int t = 0; t < 64; ++t) {
        const int cb = (t & 1) * 65536, nb = cb ^ 65536;
        const int tkn = (t + 1) & 15, psn = (t + 1) >> 4;
        const bool st = t < 63;
        {   // MH = 0
            bf16x8 af[4][2];
            RAF(0, cb)
            PH(0, 0, cb, if (st) SA(0, tkn, nb), if (st) { VM(2); } else { VM(0); })
            PH(0, 1, cb, if (st) SB(0, tkn, psn, nb), )
        }
        {   // MH = 1
            bf16x8 af[4][2];
            RAF(1, cb)
            PH(1, 0, cb, if (st) SA(1, tkn, nb), )
            PH(1, 1, cb, if (st) SB(1, tkn, psn, nb), if (st) VM(4);)
        }
        if ((t & 15) == 15) {  // end of a BN=256 u-pass: tanh epilogue
            const int ps = t >> 4;
#pragma unroll
            for (int n = 0; n < 4; n++) {
                const int u = ps * 256 + wn * 64 + (n >> 1) * 32 + (n & 1) * 16 + lr;
                const float qv = qWl[u];
                const float wv = wVl[u];
#pragma unroll
                for (int m = 0; m < 8; m++)
#pragma unroll
                    for (int r = 0; r < 4; r++) {
                        float x = acc[m][n][r] + qv;
                        float e = __expf(2.0f * x);
                        s_acc[m][r] += (1.0f - 2.0f / (e + 1.0f)) * wv;
                        acc[m][n][r] = 0.f;
                    }
            }
        }
    }
#undef PH
#undef RAF
#undef SA
#undef SB
#undef VM

    // reduce over the 16 lr-lanes
#pragma unroll
    for (int off = 1; off < 16; off <<= 1)
#pragma unroll
        for (int m = 0; m < 8; m++)
#pragma unroll
            for (int r = 0; r < 4; r++) s_acc[m][r] += __shfl_xor(s_acc[m][r], off);

    // cross-wave (4 wn) reduce via LDS, then direct store
    __syncthreads();
    if (lr == 0) {
#pragma unroll
        for (int m = 0; m < 8; m++)
#pragma unroll
            for (int r = 0; r < 4; r++)
                redl[wn * 256 + wm * 128 + (m >> 2) * 64 + (m & 3) * 16 + lk * 4 + r] = s_acc[m][r];
    }
    __syncthreads();
    if (tid < 256) {
        float s = redl[tid] + redl[256 + tid] + redl[512 + tid] + redl[768 + tid];
        scores[row0 + tid] = s;
    }
}

// ---------------- K4: softmax over T per batch (+ zero context output) ----------------
__global__ __launch_bounds__(256) void softmax_z(const float* __restrict__ scores,
                                                 float* __restrict__ wout,
                                                 float* __restrict__ out) {
    int b = blockIdx.x, tid = threadIdx.x;
    int lane = tid & 63, wave = tid >> 6;
    __shared__ float redm[4], reds[4];
    *reinterpret_cast<f32x4*>(out + (size_t)b * D_DIM + tid * 4) = (f32x4){0.f, 0.f, 0.f, 0.f};
    float v[8];
    float mx = -3.4e38f;
#pragma unroll
    for (int i = 0; i < 8; i++) {
        v[i] = scores[(size_t)b * T_SZ + tid + i * 256];
        mx = fmaxf(mx, v[i]);
    }
#pragma unroll
    for (int off = 1; off < 64; off <<= 1) mx = fmaxf(mx, __shfl_xor(mx, off));
    if (lane == 0) redm[wave] = mx;
    __syncthreads();
    mx = fmaxf(fmaxf(redm[0], redm[1]), fmaxf(redm[2], redm[3]));
    float sum = 0.f;
#pragma unroll
    for (int i = 0; i < 8; i++) {
        v[i] = __expf(v[i] - mx);
        sum += v[i];
    }
#pragma unroll
    for (int off = 1; off < 64; off <<= 1) sum += __shfl_xor(sum, off);
    if (lane == 0) reds[wave] = sum;
    __syncthreads();
    sum = reds[0] + reds[1] + reds[2] + reds[3];
    float inv = 1.0f / sum;
#pragma unroll
    for (int i = 0; i < 8; i++) wout[(size_t)b * T_SZ + tid + i * 256] = v[i] * inv;
}

// ---------------- K5: context[b,d] = sum_t w[b,t] * values_bf16[b,t,d] ----------------
__global__ __launch_bounds__(256) void context_k(const unsigned short* __restrict__ vbf,
                                                 const float* __restrict__ w,
                                                 float* __restrict__ out) {
    int b = blockIdx.x, tc = blockIdx.y;
    int d4 = threadIdx.x;
    f32x4 acc = {0.f, 0.f, 0.f, 0.f};
    const unsigned short* vb = vbf + (size_t)b * T_SZ * D_DIM;
    int t0 = tc * 64;
#pragma unroll 2
    for (int t = t0; t < t0 + 64; ++t) {
        float wt = w[(size_t)b * T_SZ + t];
        ushort4_t hv = *reinterpret_cast<const ushort4_t*>(vb + (size_t)t * D_DIM + d4 * 4);
        acc.x += wt * bf2f(hv.x);
        acc.y += wt * bf2f(hv.y);
        acc.z += wt * bf2f(hv.z);
        acc.w += wt * bf2f(hv.w);
    }
    float* o = out + (size_t)b * D_DIM + d4 * 4;
    atomicAdd(o + 0, acc.x);
    atomicAdd(o + 1, acc.y);
    atomicAdd(o + 2, acc.z);
    atomicAdd(o + 3, acc.w);
}

extern "C" void kernel_launch(void* const* d_in, const int* in_sizes, int n_in,
                              void* d_out, int out_size, void* d_ws, size_t ws_size,
                              hipStream_t stream) {
    (void)in_sizes; (void)n_in; (void)out_size; (void)ws_size;
    const float* query  = (const float*)d_in[0];
    const float* values = (const float*)d_in[1];
    const float* W1     = (const float*)d_in[2];
    const float* b1     = (const float*)d_in[3];
    const float* W2     = (const float*)d_in[4];
    const float* b2     = (const float*)d_in[5];
    const float* Wv     = (const float*)d_in[6];
    // d_in[7] = bv: softmax is shift-invariant; scores aren't an output -> unused.

    float* out  = (float*)d_out;             // [B,D] context
    float* wout = out + B_SZ * D_DIM;        // [B,T] attention weights

    const size_t VN = (size_t)B_SZ * T_SZ * D_DIM;  // 64M elems
    char* ws = (char*)d_ws;
    unsigned short* vbf = (unsigned short*)ws;                     // 128 MB
    float* scores = (float*)(ws + VN * 2);                         // 256 KB
    float* qpb = scores + 65536;                                   // 128 KB
    unsigned short* W2t = (unsigned short*)(qpb + 32768);          // 2 MB

    vconv2<<<16384, 256, 0, stream>>>(values, vbf);
    w2_transpose<<<dim3(32, 32), dim3(32, 8), 0, stream>>>(W2, W2t);
    qproj2<<<dim3(32, 16), 256, 0, stream>>>(query, W1, b1, b2, qpb);
    score_gemm9<<<256, 512, 0, stream>>>(vbf, W2t, qpb, Wv, scores);
    softmax_z<<<B_SZ, 256, 0, stream>>>(scores, wout, out);
    context_k<<<dim3(B_SZ, 32), 256, 0, stream>>>(vbf, wout, out);
}

// Round 8
// 293.747 us; speedup vs baseline: 2.6622x; 1.0028x over previous
//
#include <hip/hip_runtime.h>
#include <hip/hip_bf16.h>

#define D_DIM 1024
#define U_DIM 1024
#define B_SZ  32
#define T_SZ  2048

typedef __bf16 bf16x8 __attribute__((ext_vector_type(8)));
typedef float f32x4 __attribute__((ext_vector_type(4)));
typedef unsigned short ushort8 __attribute__((ext_vector_type(8)));
typedef unsigned short ushort4_t __attribute__((ext_vector_type(4)));

#define AS1 __attribute__((address_space(1)))
#define AS3 __attribute__((address_space(3)))

__device__ __forceinline__ unsigned short f2bf(float f) {
    union { float f; unsigned u; } v;
    v.f = f;
    unsigned r = v.u + 0x7fffu + ((v.u >> 16) & 1u);  // RNE
    return (unsigned short)(r >> 16);
}
__device__ __forceinline__ float bf2f(unsigned short h) {
    union { unsigned u; float f; } v;
    v.u = (unsigned)h << 16;
    return v.f;
}

// ---------------- K0: values fp32 -> bf16, 64B/lane ----------------
__global__ __launch_bounds__(256) void vconv2(const float* __restrict__ v,
                                              unsigned short* __restrict__ o) {
    size_t i = ((size_t)blockIdx.x * 256 + threadIdx.x) * 16;
    f32x4 a0 = *reinterpret_cast<const f32x4*>(v + i);
    f32x4 a1 = *reinterpret_cast<const f32x4*>(v + i + 4);
    f32x4 a2 = *reinterpret_cast<const f32x4*>(v + i + 8);
    f32x4 a3 = *reinterpret_cast<const f32x4*>(v + i + 12);
    ushort8 h0, h1;
    h0[0] = f2bf(a0.x); h0[1] = f2bf(a0.y); h0[2] = f2bf(a0.z); h0[3] = f2bf(a0.w);
    h0[4] = f2bf(a1.x); h0[5] = f2bf(a1.y); h0[6] = f2bf(a1.z); h0[7] = f2bf(a1.w);
    h1[0] = f2bf(a2.x); h1[1] = f2bf(a2.y); h1[2] = f2bf(a2.z); h1[3] = f2bf(a2.w);
    h1[4] = f2bf(a3.x); h1[5] = f2bf(a3.y); h1[6] = f2bf(a3.z); h1[7] = f2bf(a3.w);
    *reinterpret_cast<ushort8*>(o + i) = h0;
    *reinterpret_cast<ushort8*>(o + i + 8) = h1;
}

// ---------------- K1: W2 [D,U] fp32 -> W2t [U,D] bf16 ----------------
__global__ __launch_bounds__(256) void w2_transpose(const float* __restrict__ W2,
                                                    unsigned short* __restrict__ W2t) {
    __shared__ float tile[32][33];
    int d0 = blockIdx.x * 32, u0 = blockIdx.y * 32;
    int tx = threadIdx.x, ty = threadIdx.y;  // 32 x 8
#pragma unroll
    for (int i = 0; i < 4; i++)
        tile[ty + 8 * i][tx] = W2[(size_t)(d0 + ty + 8 * i) * U_DIM + u0 + tx];
    __syncthreads();
#pragma unroll
    for (int i = 0; i < 4; i++)
        W2t[(size_t)(u0 + ty + 8 * i) * D_DIM + d0 + tx] = f2bf(tile[tx][ty + 8 * i]);
}

// ---------------- K2: qpb[b,u] = query@W1 + b1 + b2 (fp32), K split 4-way ----------------
__global__ __launch_bounds__(256) void qproj2(const float* __restrict__ query,
                                              const float* __restrict__ W1,
                                              const float* __restrict__ b1,
                                              const float* __restrict__ b2,
                                              float* __restrict__ qpb) {
    __shared__ float red[4][64];
    const int b = blockIdx.x;
    const int u0 = blockIdx.y * 64;
    const int tid = threadIdx.x;
    const int ul = tid & 63, kq = tid >> 6;
    const int u = u0 + ul;
    float acc = 0.f;
    const float* q = query + (size_t)b * D_DIM;
#pragma unroll 4
    for (int k = kq * 256; k < kq * 256 + 256; k++)
        acc += q[k] * W1[(size_t)k * U_DIM + u];
    red[kq][ul] = acc;
    __syncthreads();
    if (tid < 64) {
        float s = red[0][tid] + red[1][tid] + red[2][tid] + red[3][tid];
        qpb[(size_t)b * U_DIM + u0 + tid] = s + b1[u0 + tid] + b2[u0 + tid];
    }
}

// ---------------- K3: fused score GEMM — m201-style deep-pipelined 4-phase tiles ----------------
// Block 256 rows; 4 u-passes of BN=256; BK=64 -> 64 K-tiles; 8 waves (wm2 x wn4),
// wave tile 128x64, acc[8][4]. LDS: 2 slots x (A 32K + B 32K) + qW/wV/red = 140 KB.
//
// Phase = { frag ds_reads; stage ops; s_barrier; lgkmcnt(0); sched0; setprio1;
//           16 MFMA; setprio0; [vmcnt gate]; sched0; s_barrier }   (pure MFMA cluster)
//
// Deep staging (into halves freed by the prior phase's closing barrier; slot of tile w = w&1):
//   P1(t): stage Bh1(t+1)   [Bh1(t-1) freed at P4(t-1)]
//   P2(t): stage Ah0(t+2)   [Ah0(t) freed at P1(t); bq0 reg-cached so Bh0 also free]
//   P4(t): stage Bh0(t+2), Ah1(t+2)  [freed at P3(t)]
// Reads: P1 af0(8)+bq0(4); P2 bq1(4); P3 af1(8) (bq0 reused from regs); P4 bq1(4).
// Per-wave vmcnt ledger (2 loads/stage-op, chronological):
//   steady in-flight entering P1(t): [Ah1(t),Bh1(t),Ah0(t+1),Bh0(t+1),Ah1(t+1)] = 10
//   G@P1-end: vmcnt(8)  retires Ah1(t),Bh1(t)      (needed P2/P3/P4 of t)
//   G@P4-end: vmcnt(10) retires Ah0(t+1),Bh0(t+1)  (needed P1 of t+1)
//   latency cover: A-halves 7 phases, B-halves 4-5 phases (>> 900cy HBM).
// Prologue: 14 loads [Ah0,Bh0,Ah1,Bh1](0),[Ah0,Bh0,Ah1](1) + vmcnt(10) -> steady from t=0.
// Tail: t=62 stages only Bh1(63); gates vmcnt(8)/vmcnt(4). t=63: no stages; vmcnt(0)@P1.
__global__ __launch_bounds__(512, 2) void score_gemm10(const unsigned short* __restrict__ vbf,
                                                       const unsigned short* __restrict__ W2t,
                                                       const float* __restrict__ qpb,
                                                       const float* __restrict__ Wv,
                                                       float* __restrict__ scores) {
    __shared__ char smem[143360];
    float* qWl = (float*)(smem + 131072);   // 1024 f32
    float* wVl = (float*)(smem + 135168);   // 1024 f32
    float* redl = (float*)(smem + 139264);  // [4][256]

    const int tid = threadIdx.x, wave = tid >> 6, lane = tid & 63;
    const int lr = lane & 15, lk = lane >> 4;
    const int wm = wave >> 2, wn = wave & 3;
    const int row0 = blockIdx.x * 256;
    const int b = row0 >> 11;

    // qpb/Wv -> LDS (epilogues issue no vmem; vmcnt ledger stays exact)
    qWl[tid]       = qpb[(size_t)b * U_DIM + tid];
    qWl[tid + 512] = qpb[(size_t)b * U_DIM + tid + 512];
    wVl[tid]       = Wv[tid];
    wVl[tid + 512] = Wv[tid + 512];

    // ds_read swizzled bases
    int pa[2], pb[2];
#pragma unroll
    for (int kk = 0; kk < 2; kk++) {
        pa[kk] = (wm * 128 + lr) * 128 + (((kk * 4 + lk) ^ (lr & 7)) << 4);
        pb[kk] = (wn * 64 + lr) * 128 + (((kk * 4 + lk) ^ (lr & 7)) << 4);
    }

    // stage addressing: LDS dest linear, global source pre-swizzled (involution)
    const int ecol = ((lane & 7) ^ (lane >> 3)) * 8;
    int aoff[2], dstA[2], boff[2], dstB[2];
#pragma unroll
    for (int j = 0; j < 2; j++) {
        const int rowA = j * 128 + wave * 8 + (lane >> 3);
        aoff[j] = (row0 + rowA) * 1024 + ecol;
        dstA[j] = j * 16384 + wave * 1024 + lane * 16;
        const int idx = wave * 2 + j, s = idx >> 2, l = idx & 3;
        const int rowB = s * 64 + l * 8 + (lane >> 3);
        boff[j] = rowB * 1024 + ecol;
        dstB[j] = 32768 + s * 8192 + l * 1024 + lane * 16;
    }

    auto SA2 = [&](int w, int h) {  // stage A-half h of tile w into slot w&1
#pragma unroll
        for (int j = 0; j < 2; j++)
            __builtin_amdgcn_global_load_lds(
                (const AS1 void*)(vbf + (size_t)(aoff[j] + h * 65536 + ((w & 15) << 6))),
                (AS3 void*)(smem + (w & 1) * 65536 + dstA[j] + h * 8192), 16, 0, 0);
    };
    auto SB2 = [&](int w, int h) {  // stage B-half h of tile w into slot w&1
#pragma unroll
        for (int j = 0; j < 2; j++)
            __builtin_amdgcn_global_load_lds(
                (const AS1 void*)(W2t + (size_t)(boff[j] + ((w >> 4) << 18) + h * 32768 +
                                                 ((w & 15) << 6))),
                (AS3 void*)(smem + (w & 1) * 65536 + dstB[j] + h * 4096), 16, 0, 0);
    };

    f32x4 acc[8][4] = {};
    float s_acc[8][4] = {};

#define VMW(N) asm volatile("s_waitcnt vmcnt(" #N ")" ::: "memory")
#define BARLG                                          \
    __builtin_amdgcn_s_barrier();                      \
    asm volatile("s_waitcnt lgkmcnt(0)" ::: "memory"); \
    __builtin_amdgcn_sched_barrier(0);
#define PEND                            \
    __builtin_amdgcn_sched_barrier(0);  \
    __builtin_amdgcn_s_barrier();
#define MFMA16(MH, NH, BQ)                                                           \
    __builtin_amdgcn_s_setprio(1);                                                   \
    _Pragma("unroll") for (int kk = 0; kk < 2; kk++)                                 \
        _Pragma("unroll") for (int ni = 0; ni < 2; ni++)                             \
            _Pragma("unroll") for (int mi = 0; mi < 4; mi++)                         \
                acc[(MH) * 4 + mi][(NH) * 2 + ni] =                                  \
                    __builtin_amdgcn_mfma_f32_16x16x32_bf16(                         \
                        af[mi][kk], BQ[ni][kk], acc[(MH) * 4 + mi][(NH) * 2 + ni], 0, 0, 0); \
    __builtin_amdgcn_s_setprio(0);

#define TILE(TT, CB, S1ON, S2ON, G1, G4)                                                  \
    {                                                                                     \
        bf16x8 af[4][2], bq0[2][2], bq1[2][2];                                            \
        _Pragma("unroll") for (int mi = 0; mi < 4; mi++)                                  \
            _Pragma("unroll") for (int kk = 0; kk < 2; kk++)                              \
                af[mi][kk] = *(const bf16x8*)(smem + (CB) + mi * 2048 + pa[kk]);          \
        _Pragma("unroll") for (int ni = 0; ni < 2; ni++)                                  \
            _Pragma("unroll") for (int kk = 0; kk < 2; kk++)                              \
                bq0[ni][kk] = *(const bf16x8*)(smem + (CB) + 32768 + ni * 2048 + pb[kk]); \
        if (S1ON) SB2((TT) + 1, 1);                                                       \
        BARLG MFMA16(0, 0, bq0) G1; PEND                                                  \
        _Pragma("unroll") for (int ni = 0; ni < 2; ni++)                                  \
            _Pragma("unroll") for (int kk = 0; kk < 2; kk++)                              \
                bq1[ni][kk] = *(const bf16x8*)(smem + (CB) + 36864 + ni * 2048 + pb[kk]); \
        if (S2ON) SA2((TT) + 2, 0);                                                       \
        BARLG MFMA16(0, 1, bq1) PEND                                                      \
        _Pragma("unroll") for (int mi = 0; mi < 4; mi++)                                  \
            _Pragma("unroll") for (int kk = 0; kk < 2; kk++)                              \
                af[mi][kk] = *(const bf16x8*)(smem + (CB) + 8192 + mi * 2048 + pa[kk]);   \
        BARLG MFMA16(1, 0, bq0) PEND                                                      \
        _Pragma("unroll") for (int ni = 0; ni < 2; ni++)                                  \
            _Pragma("unroll") for (int kk = 0; kk < 2; kk++)                              \
                bq1[ni][kk] = *(const bf16x8*)(smem + (CB) + 36864 + ni * 2048 + pb[kk]); \
        if (S2ON) { SB2((TT) + 2, 0); SA2((TT) + 2, 1); }                                 \
        BARLG MFMA16(1, 1, bq1) G4; PEND                                                  \
    }

#define EPI(PS)                                                                     \
    {                                                                               \
        const int psv = (PS);                                                       \
        _Pragma("unroll") for (int n = 0; n < 4; n++) {                             \
            const int u = psv * 256 + wn * 64 + (n >> 1) * 32 + (n & 1) * 16 + lr;  \
            const float qv = qWl[u];                                                \
            const float wv = wVl[u];                                                \
            _Pragma("unroll") for (int m = 0; m < 8; m++)                           \
                _Pragma("unroll") for (int r = 0; r < 4; r++) {                     \
                    float x = acc[m][n][r] + qv;                                    \
                    float e = __expf(2.0f * x);                                     \
                    s_acc[m][r] += (1.0f - 2.0f / (e + 1.0f)) * wv;                 \
                    acc[m][n][r] = 0.f;                                             \
                }                                                                   \
        }                                                                           \
    }

    // prologue: drain qW/wV traffic, stage in ledger order, enter steady state
    asm volatile("s_waitcnt vmcnt(0) lgkmcnt(0)" ::: "memory");
    SA2(0, 0); SB2(0, 0); SA2(0, 1); SB2(0, 1);
    SA2(1, 0); SB2(1, 0); SA2(1, 1);
    VMW(10);
    __builtin_amdgcn_sched_barrier(0);
    __builtin_amdgcn_s_barrier();

#pragma unroll 1
    for (int s2 = 0; s2 < 31; ++s2) {
        const int te = 2 * s2;
        TILE(te, 0, 1, 1, VMW(8), VMW(10))
        TILE(te + 1, 65536, 1, 1, VMW(8), VMW(10))
        if ((s2 & 7) == 7) EPI(s2 >> 3)
    }
    TILE(62, 0, 1, 0, VMW(8), VMW(4))
    TILE(63, 65536, 0, 0, VMW(0), )
    EPI(3)

#undef TILE
#undef MFMA16
#undef BARLG
#undef PEND
#undef VMW
#undef EPI

    // reduce over the 16 lr-lanes
#pragma unroll
    for (int off = 1; off < 16; off <<= 1)
#pragma unroll
        for (int m = 0; m < 8; m++)
#pragma unroll
            for (int r = 0; r < 4; r++) s_acc[m][r] += __shfl_xor(s_acc[m][r], off);

    // cross-wave (4 wn) reduce via LDS, then direct store
    __syncthreads();
    if (lr == 0) {
#pragma unroll
        for (int m = 0; m < 8; m++)
#pragma unroll
            for (int r = 0; r < 4; r++)
                redl[wn * 256 + wm * 128 + (m >> 2) * 64 + (m & 3) * 16 + lk * 4 + r] = s_acc[m][r];
    }
    __syncthreads();
    if (tid < 256) {
        float s = redl[tid] + redl[256 + tid] + redl[512 + tid] + redl[768 + tid];
        scores[row0 + tid] = s;
    }
}

// ---------------- K4: softmax over T per batch (+ zero context output) ----------------
__global__ __launch_bounds__(256) void softmax_z(const float* __restrict__ scores,
                                                 float* __restrict__ wout,
                                                 float* __restrict__ out) {
    int b = blockIdx.x, tid = threadIdx.x;
    int lane = tid & 63, wave = tid >> 6;
    __shared__ float redm[4], reds[4];
    *reinterpret_cast<f32x4*>(out + (size_t)b * D_DIM + tid * 4) = (f32x4){0.f, 0.f, 0.f, 0.f};
    float v[8];
    float mx = -3.4e38f;
#pragma unroll
    for (int i = 0; i < 8; i++) {
        v[i] = scores[(size_t)b * T_SZ + tid + i * 256];
        mx = fmaxf(mx, v[i]);
    }
#pragma unroll
    for (int off = 1; off < 64; off <<= 1) mx = fmaxf(mx, __shfl_xor(mx, off));
    if (lane == 0) redm[wave] = mx;
    __syncthreads();
    mx = fmaxf(fmaxf(redm[0], redm[1]), fmaxf(redm[2], redm[3]));
    float sum = 0.f;
#pragma unroll
    for (int i = 0; i < 8; i++) {
        v[i] = __expf(v[i] - mx);
        sum += v[i];
    }
#pragma unroll
    for (int off = 1; off < 64; off <<= 1) sum += __shfl_xor(sum, off);
    if (lane == 0) reds[wave] = sum;
    __syncthreads();
    sum = reds[0] + reds[1] + reds[2] + reds[3];
    float inv = 1.0f / sum;
#pragma unroll
    for (int i = 0; i < 8; i++) wout[(size_t)b * T_SZ + tid + i * 256] = v[i] * inv;
}

// ---------------- K5: context[b,d] = sum_t w[b,t] * values_bf16[b,t,d] ----------------
__global__ __launch_bounds__(256) void context_k(const unsigned short* __restrict__ vbf,
                                                 const float* __restrict__ w,
                                                 float* __restrict__ out) {
    int b = blockIdx.x, tc = blockIdx.y;
    int d4 = threadIdx.x;
    f32x4 acc = {0.f, 0.f, 0.f, 0.f};
    const unsigned short* vb = vbf + (size_t)b * T_SZ * D_DIM;
    int t0 = tc * 64;
#pragma unroll 2
    for (int t = t0; t < t0 + 64; ++t) {
        float wt = w[(size_t)b * T_SZ + t];
        ushort4_t hv = *reinterpret_cast<const ushort4_t*>(vb + (size_t)t * D_DIM + d4 * 4);
        acc.x += wt * bf2f(hv.x);
        acc.y += wt * bf2f(hv.y);
        acc.z += wt * bf2f(hv.z);
        acc.w += wt * bf2f(hv.w);
    }
    float* o = out + (size_t)b * D_DIM + d4 * 4;
    atomicAdd(o + 0, acc.x);
    atomicAdd(o + 1, acc.y);
    atomicAdd(o + 2, acc.z);
    atomicAdd(o + 3, acc.w);
}

extern "C" void kernel_launch(void* const* d_in, const int* in_sizes, int n_in,
                              void* d_out, int out_size, void* d_ws, size_t ws_size,
                              hipStream_t stream) {
    (void)in_sizes; (void)n_in; (void)out_size; (void)ws_size;
    const float* query  = (const float*)d_in[0];
    const float* values = (const float*)d_in[1];
    const float* W1     = (const float*)d_in[2];
    const float* b1     = (const float*)d_in[3];
    const float* W2     = (const float*)d_in[4];
    const float* b2     = (const float*)d_in[5];
    const float* Wv     = (const float*)d_in[6];
    // d_in[7] = bv: softmax is shift-invariant; scores aren't an output -> unused.

    float* out  = (float*)d_out;             // [B,D] context
    float* wout = out + B_SZ * D_DIM;        // [B,T] attention weights

    const size_t VN = (size_t)B_SZ * T_SZ * D_DIM;  // 64M elems
    char* ws = (char*)d_ws;
    unsigned short* vbf = (unsigned short*)ws;                     // 128 MB
    float* scores = (float*)(ws + VN * 2);                         // 256 KB
    float* qpb = scores + 65536;                                   // 128 KB
    unsigned short* W2t = (unsigned short*)(qpb + 32768);          // 2 MB

    vconv2<<<16384, 256, 0, stream>>>(values, vbf);
    w2_transpose<<<dim3(32, 32), dim3(32, 8), 0, stream>>>(W2, W2t);
    qproj2<<<dim3(32, 16), 256, 0, stream>>>(query, W1, b1, b2, qpb);
    score_gemm10<<<256, 512, 0, stream>>>(vbf, W2t, qpb, Wv, scores);
    softmax_z<<<B_SZ, 256, 0, stream>>>(scores, wout, out);
    context_k<<<dim3(B_SZ, 32), 256, 0, stream>>>(vbf, wout, out);
}